// Round 16
// baseline (88.831 us; speedup 1.0000x reference)
//
#include <hip/hip_runtime.h>
#include <hip/hip_bf16.h>
#include <cstdint>
#include <climits>

#define BATCH 8192
#define DIM   128
#define KBYTES 192         // 128 data i8 + 60 label bytes + 4 pad (K=192)
#define MARGIN 1.0f
#define SEPI   193548      // 2 * 6 * 127 * 127 label separator (int, exact)
#define SCALE  16.0f       // fp32 -> i8 quantization scale
#define INVS2  (1.0f / 256.0f)

typedef __attribute__((ext_vector_type(4))) int   int4v;
typedef __attribute__((ext_vector_type(4))) float f32x4;

// async 16B global -> LDS; LDS dst = wave-uniform base, HW adds lane*16
__device__ __forceinline__ void async_copy16(const void* g, void* lds) {
    __builtin_amdgcn_global_load_lds(
        (const __attribute__((address_space(1))) unsigned int*)g,
        (__attribute__((address_space(3))) unsigned int*)lds, 16, 0, 0);
}

// ---------------------------------------------------------------------------
// Kernel 1: quantize fp32 -> i8 (scale 16, clamp +-127) into label-AUGMENTED
// matrices (validated R15, absmax 0). Row (192 B): [128 data i8][60 aug:
// label lab -> bytes 6*lab..6*lab+5 = +127 (A) / -127 (B)][4 pad].
// val = sqj - 2*dot_aug = (sqj - 2*dot) + 193548*[same] -> pure max/min
// epilogue in EXACT i32. Also integer row norms + hp2/hn2 init.
// ---------------------------------------------------------------------------
__global__ __launch_bounds__(256) void bhtl_prep(
    const float* __restrict__ emb,
    const int* __restrict__ labels,
    signed char* __restrict__ EA,
    signed char* __restrict__ EB,
    int* __restrict__ sq,
    unsigned* __restrict__ hp2,
    unsigned* __restrict__ hn2)
{
    const int hw  = threadIdx.x >> 5;          // half-wave 0..7
    const int l   = threadIdx.x & 31;
    const int row = blockIdx.x * 8 + hw;
    const float4 e = ((const float4*)(emb + (size_t)row * DIM))[l];

    int a0 = (int)rintf(e.x * SCALE); a0 = min(127, max(-127, a0));
    int a1 = (int)rintf(e.y * SCALE); a1 = min(127, max(-127, a1));
    int a2 = (int)rintf(e.z * SCALE); a2 = min(127, max(-127, a2));
    int a3 = (int)rintf(e.w * SCALE); a3 = min(127, max(-127, a3));
    unsigned pa = (a0 & 255) | ((a1 & 255) << 8) | ((a2 & 255) << 16) | ((a3 & 255) << 24);
    *(unsigned*)(EA + (size_t)row * KBYTES + l * 4) = pa;
    *(unsigned*)(EB + (size_t)row * KBYTES + l * 4) = pa;   // data identical

    if (l < 16) {   // aug bytes 128..191: 4 bytes per lane
        const int lab = labels[row];
        unsigned wa = 0, wb = 0;
        #pragma unroll
        for (int b = 0; b < 4; ++b) {
            int j = l * 4 + b;                 // 0..63
            int in = (j < 60) && (j / 6 == lab);
            wa |= (unsigned)((in ?  127 : 0) & 255) << (8 * b);
            wb |= (unsigned)((in ? -127 : 0) & 255) << (8 * b);
        }
        *(unsigned*)(EA + (size_t)row * KBYTES + 128 + l * 4) = wa;
        *(unsigned*)(EB + (size_t)row * KBYTES + 128 + l * 4) = wb;
    }

    int s = a0 * a0 + a1 * a1 + a2 * a2 + a3 * a3;
    #pragma unroll
    for (int d = 1; d < 32; d <<= 1) s += __shfl_xor(s, d, 64);  // half-wave
    if (l == 0) {
        sq[row]  = s;
        hp2[row] = 0u;           // float-bits max accumulator (non-negative)
        hn2[row] = 0x7F800000u;  // +inf (min accumulator)
    }
}

// ---------------------------------------------------------------------------
// Kernel 2: fused i8 E_A @ E_B^T + int max/min epilogue.
// R15 recipe with 32-COL CHUNKS (halves the wait count: 16 iters not 32 —
// each vmcnt wait now amortized over ~2x compute):
//   2048 blocks x 64 threads; wave = 64 rows x 512 cols, 16 chunks of 32.
//   Chunk = 32 cols x 192 B = 6 KB = 6 glds. 3 wave-private buffers (18 KB)
//   + col-sq (2 KB) = 20 KB LDS -> 8 blocks/CU. ~135 VGPR -> 2+/SIMD.
//   Depth-2 prefetch: iter ch waits vmcnt(6) (drains ch's 6, leaves ch+1's
//   6 in flight), stages ch+2. Zero barriers.
//   MFMA: mfma_i32_16x16x64_i8 transposed (validated R15): lane(q,ln) elem
//   r -> row = rowbase+m*16+ln, col = jb+n*16+q*4+r.
// Swizzle (global side, validated R15): col's 12 units: u<8 -> u^(col&7);
//   u>=8 -> 8+((u-8)^(col&3)).
// Atomics fire-and-forget float-bits (exact int->float, <2^24). NO fence.
// ---------------------------------------------------------------------------
__global__ __launch_bounds__(64) void bhtl_main(
    const signed char* __restrict__ EA,
    const signed char* __restrict__ EB,
    const int* __restrict__ sq,
    unsigned* __restrict__ hp2,
    unsigned* __restrict__ hn2)
{
    __shared__ __align__(16) unsigned char B_s[3][6144];   // 3 bufs x 6 KB
    __shared__ __align__(16) int sqm[512];                 // col sq (2 KB)

    const int lane = threadIdx.x;              // 0..63
    const int q    = lane >> 4;
    const int ln   = lane & 15;
    const int rb   = blockIdx.x >> 4;          // 0..127 row band (64 rows)
    const int js   = blockIdx.x & 15;          // 0..15 col split (512 cols)
    const int rowbase = rb * 64;
    const int jbase   = js * 512;

    // ---- A fragments (64 rows, K=192) pinned: 4 m x 3 kc x 4 VGPR = 48 ----
    int4v af[4][3];
    #pragma unroll
    for (int m = 0; m < 4; ++m)
        #pragma unroll
        for (int kc = 0; kc < 3; ++kc) {
            af[m][kc] = *(const int4v*)(
                EA + (size_t)(rowbase + m * 16 + ln) * KBYTES + kc * 64 + q * 16);
            asm("" : "+v"(af[m][kc]));
        }

    // ---- stage col sq (512 ints = 2 KB = 2 glds) ----
    #pragma unroll
    for (int c = 0; c < 2; ++c)
        async_copy16(sq + jbase + (c * 64 + lane) * 4, &sqm[c * 256]);

    asm volatile("s_waitcnt vmcnt(0)" ::: "memory");   // drain prologue vmem

    // ---- B chunk stager: 32 cols x 12 units = 384 units = 6 glds ----
    auto stageB = [&](int buf, int ch) {
        const int jb = jbase + ch * 32;
        #pragma unroll
        for (int c = 0; c < 6; ++c) {
            int U   = c * 64 + lane;           // 0..383
            int col = U / 12;                  // 0..31 (magic-mul)
            int u   = U - col * 12;            // 0..11
            int g   = (u < 8) ? (u ^ (col & 7)) : (8 + ((u - 8) ^ (col & 3)));
            async_copy16(EB + (size_t)(jb + col) * KBYTES + g * 16,
                         &B_s[buf][c * 1024]);
        }
    };

    int mp[4] = {INT_MIN, INT_MIN, INT_MIN, INT_MIN};
    int mn[4] = {INT_MAX, INT_MAX, INT_MAX, INT_MAX};

    auto doIter = [&](int ch, int buf, bool doStage, int stageBuf, bool last) {
        if (last) asm volatile("s_waitcnt vmcnt(0)" ::: "memory");
        else      asm volatile("s_waitcnt vmcnt(6)" ::: "memory");

        // LDS reads for chunk ch: 2 col-groups of 16
        int4v bfr[2][3];
        #pragma unroll
        for (int n = 0; n < 2; ++n)
            #pragma unroll
            for (int kc = 0; kc < 3; ++kc) {
                const int t    = kc * 4 + q;                 // global unit 0..11
                const int unit = (t < 8) ? (t ^ (ln & 7)) : (8 + (q ^ (ln & 3)));
                bfr[n][kc] = *(const int4v*)(
                    &B_s[buf][((n * 16 + ln) * 12 + unit) * 16]);
            }
        int4v sqj[2];
        #pragma unroll
        for (int n = 0; n < 2; ++n)
            sqj[n] = *(const int4v*)(&sqm[ch * 32 + n * 16 + q * 4]);

        if (doStage) stageB(stageBuf, ch + 2);           // depth-2 prefetch

        // MFMA: 4 row-blocks x 2 col-groups x K=192 (24 x 16x16x64 i8)
        int4v acc[4][2];
        const int4v zero = {0, 0, 0, 0};
        #pragma unroll
        for (int m = 0; m < 4; ++m)
            #pragma unroll
            for (int n = 0; n < 2; ++n) acc[m][n] = zero;
        #pragma unroll
        for (int kc = 0; kc < 3; ++kc)
            #pragma unroll
            for (int m = 0; m < 4; ++m)
                #pragma unroll
                for (int n = 0; n < 2; ++n)
                    acc[m][n] = __builtin_amdgcn_mfma_i32_16x16x64_i8(
                        bfr[n][kc], af[m][kc], acc[m][n], 0, 0, 0);  // transposed

        // epilogue: val = sqj - 2*dot_aug (int, exact)
        #pragma unroll
        for (int m = 0; m < 4; ++m)
            #pragma unroll
            for (int n = 0; n < 2; ++n)
                #pragma unroll
                for (int r = 0; r < 4; ++r) {
                    int val = sqj[n][r] - 2 * acc[m][n][r];
                    mp[m] = max(mp[m], val);
                    mn[m] = min(mn[m], val);
                }
    };

    stageB(0, 0);
    stageB(1, 1);

    // 16 iters: 0..14 in 5 groups of 3 (buf = ch%3), then iter 15 (last).
    #pragma unroll 1
    for (int base = 0; base < 15; base += 3) {
        doIter(base,     0, base     <= 13, 2, false);
        doIter(base + 1, 1, base + 1 <= 13, 0, false);
        doIter(base + 2, 2, base + 2 <= 13, 1, false);
    }
    doIter(15, 0, false, 0, true);

    // ---- reduce over the 4 q-lanes sharing each row, then atomics ----
    #pragma unroll
    for (int m = 0; m < 4; ++m) {
        int a = mp[m], b = mn[m];
        a = max(a, __shfl_xor(a, 16, 64));
        a = max(a, __shfl_xor(a, 32, 64));
        b = min(b, __shfl_xor(b, 16, 64));
        b = min(b, __shfl_xor(b, 32, 64));
        if (q == 0) {
            const int row = rowbase + m * 16 + ln;
            const int sqi = sq[row];
            // d^2/256: ints < 2^24 -> float conversion exact; clamp>=0 keeps
            // uint order == float order; no-same-class splits self-correct.
            float hpf = fmaxf((float)(sqi + a - SEPI) * INVS2, 0.0f);
            float hnf = fmaxf((float)(sqi + b) * INVS2, 0.0f);
            atomicMax(&hp2[row], __float_as_uint(hpf));
            atomicMin(&hn2[row], __float_as_uint(hnf));
        }
    }
}

// ---------------------------------------------------------------------------
// Kernel 3: per-anchor loss + mean. Single block, deterministic output.
// ---------------------------------------------------------------------------
__global__ __launch_bounds__(1024) void bhtl_final(
    const unsigned* __restrict__ hp2,
    const unsigned* __restrict__ hn2,
    float* __restrict__ out)
{
    __shared__ float red[16];
    float sum = 0.f;
    for (int i = threadIdx.x; i < BATCH; i += 1024) {
        float hp = sqrtf(__uint_as_float(hp2[i]));
        float hn = sqrtf(__uint_as_float(hn2[i]));
        sum += fmaxf(hp - hn + MARGIN, 0.f);
    }
    #pragma unroll
    for (int d = 1; d < 64; d <<= 1) sum += __shfl_xor(sum, d, 64);
    int wv = threadIdx.x >> 6;
    if ((threadIdx.x & 63) == 0) red[wv] = sum;
    __syncthreads();
    if (threadIdx.x < 64) {
        float v = (threadIdx.x < 16) ? red[threadIdx.x] : 0.f;
        #pragma unroll
        for (int d = 1; d < 16; d <<= 1) v += __shfl_xor(v, d, 64);
        if (threadIdx.x == 0) out[0] = v / (float)BATCH;
    }
}

// ---------------------------------------------------------------------------
extern "C" void kernel_launch(void* const* d_in, const int* in_sizes, int n_in,
                              void* d_out, int out_size, void* d_ws, size_t ws_size,
                              hipStream_t stream)
{
    const float* emb    = (const float*)d_in[0];
    const int*   labels = (const int*)d_in[1];
    float*       out    = (float*)d_out;

    char* ws = (char*)d_ws;
    signed char* EA  = (signed char*)ws;                              // 1.5 MiB
    signed char* EB  = (signed char*)(ws + 2 * 1024 * 1024);          // 1.5 MiB
    int*      sq   = (int*)     (ws + 4 * 1024 * 1024);               // 32 KiB
    unsigned* hp2  = (unsigned*)(ws + 4 * 1024 * 1024 + 32 * 1024);   // 32 KiB
    unsigned* hn2  = (unsigned*)(ws + 4 * 1024 * 1024 + 64 * 1024);   // 32 KiB

    bhtl_prep<<<BATCH / 8, 256, 0, stream>>>(emb, labels, EA, EB, sq, hp2, hn2);
    bhtl_main<<<2048, 64, 0, stream>>>(EA, EB, sq, hp2, hn2);
    bhtl_final<<<1, 1024, 0, stream>>>(hp2, hn2, out);
}

// Round 17
// 81.186 us; speedup vs baseline: 1.0942x; 1.0942x over previous
//
#include <hip/hip_runtime.h>
#include <hip/hip_bf16.h>
#include <cstdint>
#include <climits>

#define BATCH 8192
#define DIM   128
#define KBYTES 192         // 128 data i8 + 60 label bytes + 4 pad (K=192)
#define MARGIN 1.0f
#define SEPI   193548      // 2 * 6 * 127 * 127 label separator (int, exact)
#define SCALE  16.0f       // fp32 -> i8 quantization scale
#define INVS2  (1.0f / 256.0f)

typedef __attribute__((ext_vector_type(4))) int   int4v;
typedef __attribute__((ext_vector_type(4))) float f32x4;

// async 16B global -> LDS; LDS dst = wave-uniform base, HW adds lane*16
__device__ __forceinline__ void async_copy16(const void* g, void* lds) {
    __builtin_amdgcn_global_load_lds(
        (const __attribute__((address_space(1))) unsigned int*)g,
        (__attribute__((address_space(3))) unsigned int*)lds, 16, 0, 0);
}

// ---------------------------------------------------------------------------
// Kernel 1: quantize fp32 -> i8 (scale 16, clamp +-127) into label-AUGMENTED
// matrices (validated R15, absmax 0). Row (192 B): [128 data i8][60 aug:
// label lab -> bytes 6*lab..6*lab+5 = +127 (A) / -127 (B)][4 pad].
// val = sqj - 2*dot_aug = (sqj - 2*dot) + 193548*[same] -> pure max/min
// epilogue in EXACT i32 (everything < 2^24, float conversion exact).
// Also per-row integer squared norms + hp2/hn2 init.
// ---------------------------------------------------------------------------
__global__ __launch_bounds__(256) void bhtl_prep(
    const float* __restrict__ emb,
    const int* __restrict__ labels,
    signed char* __restrict__ EA,
    signed char* __restrict__ EB,
    int* __restrict__ sq,
    unsigned* __restrict__ hp2,
    unsigned* __restrict__ hn2)
{
    const int hw  = threadIdx.x >> 5;          // half-wave 0..7
    const int l   = threadIdx.x & 31;
    const int row = blockIdx.x * 8 + hw;
    const float4 e = ((const float4*)(emb + (size_t)row * DIM))[l];

    int a0 = (int)rintf(e.x * SCALE); a0 = min(127, max(-127, a0));
    int a1 = (int)rintf(e.y * SCALE); a1 = min(127, max(-127, a1));
    int a2 = (int)rintf(e.z * SCALE); a2 = min(127, max(-127, a2));
    int a3 = (int)rintf(e.w * SCALE); a3 = min(127, max(-127, a3));
    unsigned pa = (a0 & 255) | ((a1 & 255) << 8) | ((a2 & 255) << 16) | ((a3 & 255) << 24);
    *(unsigned*)(EA + (size_t)row * KBYTES + l * 4) = pa;
    *(unsigned*)(EB + (size_t)row * KBYTES + l * 4) = pa;   // data identical

    if (l < 16) {   // aug bytes 128..191: 4 bytes per lane
        const int lab = labels[row];
        unsigned wa = 0, wb = 0;
        #pragma unroll
        for (int b = 0; b < 4; ++b) {
            int j = l * 4 + b;                 // 0..63
            int in = (j < 60) && (j / 6 == lab);
            wa |= (unsigned)((in ?  127 : 0) & 255) << (8 * b);
            wb |= (unsigned)((in ? -127 : 0) & 255) << (8 * b);
        }
        *(unsigned*)(EA + (size_t)row * KBYTES + 128 + l * 4) = wa;
        *(unsigned*)(EB + (size_t)row * KBYTES + 128 + l * 4) = wb;
    }

    int s = a0 * a0 + a1 * a1 + a2 * a2 + a3 * a3;
    #pragma unroll
    for (int d = 1; d < 32; d <<= 1) s += __shfl_xor(s, d, 64);  // half-wave
    if (l == 0) {
        sq[row]  = s;
        hp2[row] = 0u;           // float-bits max accumulator (non-negative)
        hn2[row] = 0x7F800000u;  // +inf (min accumulator)
    }
}

// ---------------------------------------------------------------------------
// Kernel 2: fused i8 E_A @ E_B^T + int max/min epilogue.
// R15 structure (session best, 81.0 us total): wave-private glds staging,
// zero barriers, 16-col chunks, depth-2 prefetch via 3 buffers, explicit
// vmcnt(3)/vmcnt(0) discipline, i8 aug epilogue:
//   2048 blocks x 64 threads; wave = 64 rows x 512 cols, 32 chunks of 16.
//   Chunk = 16 cols x 192 B = 3 KB = 3 glds. 3 wave-private buffers (9 KB)
//   + col-sq (2 KB) = 11 KB LDS -> 8 blocks/CU all resident.
//   MFMA: mfma_i32_16x16x64_i8 transposed (validated R15): lane(q,ln) elem
//   r -> row = rowbase+m*16+ln, col = jb+q*4+r.
// Swizzle (global side): col's 12 units: u<8 -> u^(col&7); u>=8 ->
//   8+((u-8)^(col&3)). Read unit for t=kc*4+q: t<8 -> t^(ln&7), else
//   8+(q^(ln&3)).
// Atomics fire-and-forget float-bits (exact int->float, <2^24). NO fence.
// ---------------------------------------------------------------------------
__global__ __launch_bounds__(64) void bhtl_main(
    const signed char* __restrict__ EA,
    const signed char* __restrict__ EB,
    const int* __restrict__ sq,
    unsigned* __restrict__ hp2,
    unsigned* __restrict__ hn2)
{
    __shared__ __align__(16) unsigned char B_s[3][3072];   // 3 bufs x 3 KB
    __shared__ __align__(16) int sqm[512];                 // col sq (2 KB)

    const int lane = threadIdx.x;              // 0..63
    const int q    = lane >> 4;
    const int ln   = lane & 15;
    const int rb   = blockIdx.x >> 4;          // 0..127 row band (64 rows)
    const int js   = blockIdx.x & 15;          // 0..15 col split (512 cols)
    const int rowbase = rb * 64;
    const int jbase   = js * 512;

    // ---- A fragments (64 rows, K=192) pinned: 4 m x 3 kc x 4 VGPR = 48 ----
    int4v af[4][3];
    #pragma unroll
    for (int m = 0; m < 4; ++m)
        #pragma unroll
        for (int kc = 0; kc < 3; ++kc) {
            af[m][kc] = *(const int4v*)(
                EA + (size_t)(rowbase + m * 16 + ln) * KBYTES + kc * 64 + q * 16);
            asm("" : "+v"(af[m][kc]));
        }

    // ---- stage col sq (512 ints = 2 KB = 2 glds) ----
    #pragma unroll
    for (int c = 0; c < 2; ++c)
        async_copy16(sq + jbase + (c * 64 + lane) * 4, &sqm[c * 256]);

    asm volatile("s_waitcnt vmcnt(0)" ::: "memory");   // drain prologue vmem

    // ---- B chunk stager: 16 cols x 12 units = 192 units = 3 glds ----
    auto stageB = [&](int buf, int ch) {
        const int jb = jbase + ch * 16;
        #pragma unroll
        for (int c = 0; c < 3; ++c) {
            int U   = c * 64 + lane;           // 0..191
            int col = U / 12;                  // 0..15 (magic-mul)
            int u   = U - col * 12;            // 0..11
            int g   = (u < 8) ? (u ^ (col & 7)) : (8 + ((u - 8) ^ (col & 3)));
            async_copy16(EB + (size_t)(jb + col) * KBYTES + g * 16,
                         &B_s[buf][c * 1024]);
        }
    };

    int mp[4] = {INT_MIN, INT_MIN, INT_MIN, INT_MIN};
    int mn[4] = {INT_MAX, INT_MAX, INT_MAX, INT_MAX};

    auto doIter = [&](int ch, int buf, bool doStage, int stageBuf, bool last) {
        if (last) asm volatile("s_waitcnt vmcnt(0)" ::: "memory");
        else      asm volatile("s_waitcnt vmcnt(3)" ::: "memory");

        // LDS reads for chunk ch
        int4v bfr[3];
        #pragma unroll
        for (int kc = 0; kc < 3; ++kc) {
            const int t    = kc * 4 + q;                 // global unit 0..11
            const int unit = (t < 8) ? (t ^ (ln & 7)) : (8 + (q ^ (ln & 3)));
            bfr[kc] = *(const int4v*)(&B_s[buf][(ln * 12 + unit) * 16]);
        }
        int4v sqj = *(const int4v*)(&sqm[ch * 16 + q * 4]);

        if (doStage) stageB(stageBuf, ch + 2);           // depth-2 prefetch

        // MFMA: 4 row-blocks x K=192 (3 x 16x16x64 i8)
        int4v acc[4];
        const int4v zero = {0, 0, 0, 0};
        #pragma unroll
        for (int m = 0; m < 4; ++m) acc[m] = zero;
        #pragma unroll
        for (int kc = 0; kc < 3; ++kc)
            #pragma unroll
            for (int m = 0; m < 4; ++m)
                acc[m] = __builtin_amdgcn_mfma_i32_16x16x64_i8(
                    bfr[kc], af[m][kc], acc[m], 0, 0, 0);   // transposed

        // epilogue: val = sqj - 2*dot_aug (int, exact)
        #pragma unroll
        for (int m = 0; m < 4; ++m)
            #pragma unroll
            for (int r = 0; r < 4; ++r) {
                int val = sqj[r] - 2 * acc[m][r];
                mp[m] = max(mp[m], val);
                mn[m] = min(mn[m], val);
            }
    };

    stageB(0, 0);
    stageB(1, 1);

    #pragma unroll 1
    for (int base = 0; base < 30; base += 3) {
        doIter(base,     0, true, 2, false);
        doIter(base + 1, 1, true, 0, false);
        doIter(base + 2, 2, base + 2 < 30, 1, false);
    }
    doIter(30, 0, false, 0, false);
    doIter(31, 1, false, 0, true);

    // ---- reduce over the 4 q-lanes sharing each row, then atomics ----
    #pragma unroll
    for (int m = 0; m < 4; ++m) {
        int a = mp[m], b = mn[m];
        a = max(a, __shfl_xor(a, 16, 64));
        a = max(a, __shfl_xor(a, 32, 64));
        b = min(b, __shfl_xor(b, 16, 64));
        b = min(b, __shfl_xor(b, 32, 64));
        if (q == 0) {
            const int row = rowbase + m * 16 + ln;
            const int sqi = sq[row];
            // d^2/256: ints < 2^24 -> float conversion exact; clamp>=0 keeps
            // uint order == float order; no-same-class splits self-correct.
            float hpf = fmaxf((float)(sqi + a - SEPI) * INVS2, 0.0f);
            float hnf = fmaxf((float)(sqi + b) * INVS2, 0.0f);
            atomicMax(&hp2[row], __float_as_uint(hpf));
            atomicMin(&hn2[row], __float_as_uint(hnf));
        }
    }
}

// ---------------------------------------------------------------------------
// Kernel 3: per-anchor loss + mean. Single block, deterministic output.
// ---------------------------------------------------------------------------
__global__ __launch_bounds__(1024) void bhtl_final(
    const unsigned* __restrict__ hp2,
    const unsigned* __restrict__ hn2,
    float* __restrict__ out)
{
    __shared__ float red[16];
    float sum = 0.f;
    for (int i = threadIdx.x; i < BATCH; i += 1024) {
        float hp = sqrtf(__uint_as_float(hp2[i]));
        float hn = sqrtf(__uint_as_float(hn2[i]));
        sum += fmaxf(hp - hn + MARGIN, 0.f);
    }
    #pragma unroll
    for (int d = 1; d < 64; d <<= 1) sum += __shfl_xor(sum, d, 64);
    int wv = threadIdx.x >> 6;
    if ((threadIdx.x & 63) == 0) red[wv] = sum;
    __syncthreads();
    if (threadIdx.x < 64) {
        float v = (threadIdx.x < 16) ? red[threadIdx.x] : 0.f;
        #pragma unroll
        for (int d = 1; d < 16; d <<= 1) v += __shfl_xor(v, d, 64);
        if (threadIdx.x == 0) out[0] = v / (float)BATCH;
    }
}

// ---------------------------------------------------------------------------
extern "C" void kernel_launch(void* const* d_in, const int* in_sizes, int n_in,
                              void* d_out, int out_size, void* d_ws, size_t ws_size,
                              hipStream_t stream)
{
    const float* emb    = (const float*)d_in[0];
    const int*   labels = (const int*)d_in[1];
    float*       out    = (float*)d_out;

    char* ws = (char*)d_ws;
    signed char* EA  = (signed char*)ws;                              // 1.5 MiB
    signed char* EB  = (signed char*)(ws + 2 * 1024 * 1024);          // 1.5 MiB
    int*      sq   = (int*)     (ws + 4 * 1024 * 1024);               // 32 KiB
    unsigned* hp2  = (unsigned*)(ws + 4 * 1024 * 1024 + 32 * 1024);   // 32 KiB
    unsigned* hn2  = (unsigned*)(ws + 4 * 1024 * 1024 + 64 * 1024);   // 32 KiB

    bhtl_prep<<<BATCH / 8, 256, 0, stream>>>(emb, labels, EA, EB, sq, hp2, hn2);
    bhtl_main<<<2048, 64, 0, stream>>>(EA, EB, sq, hp2, hn2);
    bhtl_final<<<1, 1024, 0, stream>>>(hp2, hn2, out);
}